// Round 1
// baseline (4439.491 us; speedup 1.0000x reference)
//
#include <hip/hip_runtime.h>
#include <hip/hip_bf16.h>
#include <math.h>

// Shapes:
//  x0 = corr reshaped: (256, 16,16,16,16)  [b, d, h, w, t], contiguous
//  L1: w1 (17,17,9,9) pad 4 -> y1 (256, 8,8,16,16), relu
//  L2: w2 (7,7,7,7)  pad 3 -> y2 same shape, relu
//  L3: w3 (5,5,5,5)  pad 2 -> relu
//  L4: w4 (3,3,3,3)  pad 1 -> relu
//  L5: w5 (8,8,1,1)  pad 0 -> (256,1,1,16,16), sigmoid -> out (256,1,16,16)

__global__ __launch_bounds__(256) void conv_l1(const float* __restrict__ x,
                                               const float* __restrict__ w1,
                                               const float* __restrict__ b1,
                                               float* __restrict__ y) {
  __shared__ float Xs[4][16][16][16];  // 64 KB: chunk of 4 d-slices
  const int blk = blockIdx.x;
  const int b = blk >> 1;
  const int jbase = (blk & 1) * 2;
  const int tid = threadIdx.x;
  const float* xb = x + (size_t)b * 65536;
  const float bias = b1[0];

  for (int jj = 0; jj < 2; ++jj) {
    const int idx = tid + 256 * (jbase + jj);  // (d_o*8 + h_o)*16 + w_o
    const int w_o = idx & 15;
    const int h_o = (idx >> 4) & 7;
    const int d_o = idx >> 7;                  // wave-uniform
    float acc[16];
#pragma unroll
    for (int t = 0; t < 16; ++t) acc[t] = 0.f;

    for (int c = 0; c < 4; ++c) {
      __syncthreads();
      {
        const float4* src = (const float4*)(xb + c * 16384);
        float4* dst = (float4*)&Xs[0][0][0][0];
        for (int i = tid; i < 4096; i += 256) dst[i] = src[i];
      }
      __syncthreads();

      for (int dd = 0; dd < 4; ++dd) {
        const int d_i = c * 4 + dd;
        const int kd = d_i - d_o + 4;
        if (kd < 0 || kd >= 17) continue;  // wave-uniform skip
        for (int h_i = 0; h_i < 16; ++h_i) {
          const int kh = h_i - h_o + 4;
          const bool vh = (kh >= 0) && (kh < 17);
          const int khc = vh ? kh : 0;
          const float* wrow = w1 + (kd * 17 + khc) * 81;
          for (int kw = 0; kw < 9; ++kw) {
            const int w_i = w_o + kw - 4;
            const bool vin = (w_i >= 0) && (w_i < 16);
            const bool vw = vh && vin;
            const int wic = vin ? w_i : 0;
            const float* xr = &Xs[dd][h_i][wic][0];
            float xv[16];
#pragma unroll
            for (int t = 0; t < 16; t += 4) {
              float4 v = *(const float4*)(xr + t);
              xv[t] = v.x; xv[t + 1] = v.y; xv[t + 2] = v.z; xv[t + 3] = v.w;
            }
            float wgt[9];
#pragma unroll
            for (int kt = 0; kt < 9; ++kt)
              wgt[kt] = vw ? wrow[kw * 9 + kt] : 0.f;
#pragma unroll
            for (int kt = 0; kt < 9; ++kt) {
#pragma unroll
              for (int t_o = 0; t_o < 16; ++t_o) {
                const int t_i = t_o + kt - 4;
                if (t_i >= 0 && t_i < 16) acc[t_o] += xv[t_i] * wgt[kt];
              }
            }
          }
        }
      }
    }

    float* yp = y + (size_t)b * 16384 + (size_t)idx * 16;
#pragma unroll
    for (int t = 0; t < 16; t += 4) {
      float4 v;
      v.x = fmaxf(acc[t] + bias, 0.f);
      v.y = fmaxf(acc[t + 1] + bias, 0.f);
      v.z = fmaxf(acc[t + 2] + bias, 0.f);
      v.w = fmaxf(acc[t + 3] + bias, 0.f);
      *(float4*)(yp + t) = v;
    }
  }
}

template <int KSZ, int PAD>
__global__ __launch_bounds__(256) void conv_mid(const float* __restrict__ x,
                                                const float* __restrict__ w,
                                                const float* __restrict__ bptr,
                                                float* __restrict__ y) {
  __shared__ float Xs[8][8][16][16];  // 64 KB: whole image
  const int blk = blockIdx.x;
  const int b = blk >> 1;
  const int jbase = (blk & 1) * 2;
  const int tid = threadIdx.x;
  const float* xb = x + (size_t)b * 16384;
  {
    const float4* src = (const float4*)xb;
    float4* dst = (float4*)&Xs[0][0][0][0];
    for (int i = tid; i < 4096; i += 256) dst[i] = src[i];
  }
  __syncthreads();
  const float bias = bptr[0];

  for (int jj = 0; jj < 2; ++jj) {
    const int idx = tid + 256 * (jbase + jj);
    const int w_o = idx & 15;
    const int h_o = (idx >> 4) & 7;
    const int d_o = idx >> 7;  // wave-uniform
    float acc[16];
#pragma unroll
    for (int t = 0; t < 16; ++t) acc[t] = 0.f;

    for (int d_i = 0; d_i < 8; ++d_i) {
      const int kd = d_i - d_o + PAD;
      if (kd < 0 || kd >= KSZ) continue;  // wave-uniform skip
      for (int h_i = 0; h_i < 8; ++h_i) {
        const int kh = h_i - h_o + PAD;
        const bool vh = (kh >= 0) && (kh < KSZ);
        const int khc = vh ? kh : 0;
        const float* wrow = w + (kd * KSZ + khc) * (KSZ * KSZ);
        for (int kw = 0; kw < KSZ; ++kw) {
          const int w_i = w_o + kw - PAD;
          const bool vin = (w_i >= 0) && (w_i < 16);
          const bool vw = vh && vin;
          const int wic = vin ? w_i : 0;
          const float* xr = &Xs[d_i][h_i][wic][0];
          float xv[16];
#pragma unroll
          for (int t = 0; t < 16; t += 4) {
            float4 v = *(const float4*)(xr + t);
            xv[t] = v.x; xv[t + 1] = v.y; xv[t + 2] = v.z; xv[t + 3] = v.w;
          }
          float wgt[KSZ];
#pragma unroll
          for (int kt = 0; kt < KSZ; ++kt)
            wgt[kt] = vw ? wrow[kw * KSZ + kt] : 0.f;
#pragma unroll
          for (int kt = 0; kt < KSZ; ++kt) {
#pragma unroll
            for (int t_o = 0; t_o < 16; ++t_o) {
              const int t_i = t_o + kt - PAD;
              if (t_i >= 0 && t_i < 16) acc[t_o] += xv[t_i] * wgt[kt];
            }
          }
        }
      }
    }

    float* yp = y + (size_t)b * 16384 + (size_t)idx * 16;
#pragma unroll
    for (int t = 0; t < 16; t += 4) {
      float4 v;
      v.x = fmaxf(acc[t] + bias, 0.f);
      v.y = fmaxf(acc[t + 1] + bias, 0.f);
      v.z = fmaxf(acc[t + 2] + bias, 0.f);
      v.w = fmaxf(acc[t + 3] + bias, 0.f);
      *(float4*)(yp + t) = v;
    }
  }
}

__global__ __launch_bounds__(256) void conv_l5(const float* __restrict__ x,
                                               const float* __restrict__ w5,
                                               const float* __restrict__ b5,
                                               float* __restrict__ out) {
  const int b = blockIdx.x;
  const int tid = threadIdx.x;  // = w*16 + t
  const float* xb = x + (size_t)b * 16384 + tid;
  float s = b5[0];
#pragma unroll
  for (int k = 0; k < 64; ++k) s += xb[k * 256] * w5[k];
  out[(size_t)b * 256 + tid] = 1.f / (1.f + expf(-s));
}

extern "C" void kernel_launch(void* const* d_in, const int* in_sizes, int n_in,
                              void* d_out, int out_size, void* d_ws, size_t ws_size,
                              hipStream_t stream) {
  const float* corr = (const float*)d_in[0];
  const float* w1 = (const float*)d_in[1];
  const float* b1 = (const float*)d_in[2];
  const float* w2 = (const float*)d_in[3];
  const float* b2 = (const float*)d_in[4];
  const float* w3 = (const float*)d_in[5];
  const float* b3 = (const float*)d_in[6];
  const float* w4 = (const float*)d_in[7];
  const float* b4 = (const float*)d_in[8];
  const float* w5 = (const float*)d_in[9];
  const float* b5 = (const float*)d_in[10];

  float* y1 = (float*)d_ws;                       // 16 MB
  float* y2 = y1 + (size_t)256 * 16384;           // 16 MB

  conv_l1<<<512, 256, 0, stream>>>(corr, w1, b1, y1);
  conv_mid<7, 3><<<512, 256, 0, stream>>>(y1, w2, b2, y2);
  conv_mid<5, 2><<<512, 256, 0, stream>>>(y2, w3, b3, y1);
  conv_mid<3, 1><<<512, 256, 0, stream>>>(y1, w4, b4, y2);
  conv_l5<<<256, 256, 0, stream>>>(y2, w5, b5, (float*)d_out);
}

// Round 2
// 3679.454 us; speedup vs baseline: 1.2066x; 1.2066x over previous
//
#include <hip/hip_runtime.h>
#include <hip/hip_bf16.h>
#include <math.h>

// Shapes:
//  x0 = corr reshaped: (256, 16,16,16,16)  [b, d, h, w, t], contiguous
//  L1: w1 (17,17,9,9) pad 4 -> y1 (256, 8,8,16,16), relu
//  L2: w2 (7,7,7,7)  pad 3 -> y2 same shape, relu
//  L3: w3 (5,5,5,5)  pad 2 -> relu
//  L4: w4 (3,3,3,3)  pad 1 -> relu
//  L5: w5 (8,8,1,1)  pad 0 -> (256,1,1,16,16), sigmoid -> out (256,1,16,16)
//
// R2 change: LDS row stride padded 16 -> 20 words (80B). With stride 16,
// ds_read_b128 across lanes w=0..15 hit banks {0,16} only (8 banks for 256
// words -> 4x bank cycles; SQ_LDS_BANK_CONFLICT ~1.6e9). Stride 20 spreads
// start banks over all 32 -> minimum 2 words/bank. 20 words = 80B keeps 16B
// alignment for b128.

#define RS 20  // padded row stride in words

__global__ __launch_bounds__(256) void conv_l1(const float* __restrict__ x,
                                               const float* __restrict__ w1,
                                               const float* __restrict__ b1,
                                               float* __restrict__ y) {
  __shared__ float Xs[3 * 16 * 16 * RS];  // 3 d-slices, padded rows: 60 KB
  const int blk = blockIdx.x;
  const int b = blk >> 1;
  const int jbase = (blk & 1) * 2;
  const int tid = threadIdx.x;
  const float* xb = x + (size_t)b * 65536;
  const float bias = b1[0];

  for (int jj = 0; jj < 2; ++jj) {
    const int idx = tid + 256 * (jbase + jj);  // (d_o*8 + h_o)*16 + w_o
    const int w_o = idx & 15;
    const int h_o = (idx >> 4) & 7;
    const int d_o = idx >> 7;                  // wave-uniform
    float acc[16];
#pragma unroll
    for (int t = 0; t < 16; ++t) acc[t] = 0.f;

    for (int c = 0; c < 6; ++c) {
      const int nsl = (c == 5) ? 1 : 3;  // slices in this chunk
      __syncthreads();
      {
        const float4* src = (const float4*)(xb + c * 3 * 4096);
        const int nf4 = nsl * 1024;  // 256 rows/slice * 4 f4/row
        for (int i = tid; i < nf4; i += 256) {
          const int r = i >> 2, t4 = i & 3;
          *(float4*)&Xs[r * RS + t4 * 4] = src[i];
        }
      }
      __syncthreads();

      for (int dd = 0; dd < nsl; ++dd) {
        const int d_i = c * 3 + dd;
        const int kd = d_i - d_o + 4;
        if (kd < 0 || kd >= 17) continue;  // wave-uniform skip
        for (int h_i = 0; h_i < 16; ++h_i) {
          const int kh = h_i - h_o + 4;
          const bool vh = (kh >= 0) && (kh < 17);
          const int khc = vh ? kh : 0;
          const float* wrow = w1 + (kd * 17 + khc) * 81;
          for (int kw = 0; kw < 9; ++kw) {
            const int w_i = w_o + kw - 4;
            const bool vin = (w_i >= 0) && (w_i < 16);
            const bool vw = vh && vin;
            const int wic = vin ? w_i : 0;
            const float* xr = &Xs[((dd * 16 + h_i) * 16 + wic) * RS];
            float xv[16];
#pragma unroll
            for (int t = 0; t < 16; t += 4) {
              float4 v = *(const float4*)(xr + t);
              xv[t] = v.x; xv[t + 1] = v.y; xv[t + 2] = v.z; xv[t + 3] = v.w;
            }
            float wgt[9];
#pragma unroll
            for (int kt = 0; kt < 9; ++kt)
              wgt[kt] = vw ? wrow[kw * 9 + kt] : 0.f;
#pragma unroll
            for (int kt = 0; kt < 9; ++kt) {
#pragma unroll
              for (int t_o = 0; t_o < 16; ++t_o) {
                const int t_i = t_o + kt - 4;
                if (t_i >= 0 && t_i < 16) acc[t_o] += xv[t_i] * wgt[kt];
              }
            }
          }
        }
      }
    }

    float* yp = y + (size_t)b * 16384 + (size_t)idx * 16;
#pragma unroll
    for (int t = 0; t < 16; t += 4) {
      float4 v;
      v.x = fmaxf(acc[t] + bias, 0.f);
      v.y = fmaxf(acc[t + 1] + bias, 0.f);
      v.z = fmaxf(acc[t + 2] + bias, 0.f);
      v.w = fmaxf(acc[t + 3] + bias, 0.f);
      *(float4*)(yp + t) = v;
    }
  }
}

template <int KSZ, int PAD>
__global__ __launch_bounds__(256) void conv_mid(const float* __restrict__ x,
                                                const float* __restrict__ w,
                                                const float* __restrict__ bptr,
                                                float* __restrict__ y) {
  __shared__ float Xs[8 * 8 * 16 * RS];  // whole image, padded rows: 50 KB
  const int blk = blockIdx.x;
  const int b = blk >> 1;
  const int jbase = (blk & 1) * 2;
  const int tid = threadIdx.x;
  const float* xb = x + (size_t)b * 16384;
  {
    const float4* src = (const float4*)xb;
    for (int i = tid; i < 4096; i += 256) {
      const int r = i >> 2, t4 = i & 3;
      *(float4*)&Xs[r * RS + t4 * 4] = src[i];
    }
  }
  __syncthreads();
  const float bias = bptr[0];

  for (int jj = 0; jj < 2; ++jj) {
    const int idx = tid + 256 * (jbase + jj);
    const int w_o = idx & 15;
    const int h_o = (idx >> 4) & 7;
    const int d_o = idx >> 7;  // wave-uniform
    float acc[16];
#pragma unroll
    for (int t = 0; t < 16; ++t) acc[t] = 0.f;

    for (int d_i = 0; d_i < 8; ++d_i) {
      const int kd = d_i - d_o + PAD;
      if (kd < 0 || kd >= KSZ) continue;  // wave-uniform skip
      for (int h_i = 0; h_i < 8; ++h_i) {
        const int kh = h_i - h_o + PAD;
        const bool vh = (kh >= 0) && (kh < KSZ);
        const int khc = vh ? kh : 0;
        const float* wrow = w + (kd * KSZ + khc) * (KSZ * KSZ);
        for (int kw = 0; kw < KSZ; ++kw) {
          const int w_i = w_o + kw - PAD;
          const bool vin = (w_i >= 0) && (w_i < 16);
          const bool vw = vh && vin;
          const int wic = vin ? w_i : 0;
          const float* xr = &Xs[((d_i * 8 + h_i) * 16 + wic) * RS];
          float xv[16];
#pragma unroll
          for (int t = 0; t < 16; t += 4) {
            float4 v = *(const float4*)(xr + t);
            xv[t] = v.x; xv[t + 1] = v.y; xv[t + 2] = v.z; xv[t + 3] = v.w;
          }
          float wgt[KSZ];
#pragma unroll
          for (int kt = 0; kt < KSZ; ++kt)
            wgt[kt] = vw ? wrow[kw * KSZ + kt] : 0.f;
#pragma unroll
          for (int kt = 0; kt < KSZ; ++kt) {
#pragma unroll
            for (int t_o = 0; t_o < 16; ++t_o) {
              const int t_i = t_o + kt - PAD;
              if (t_i >= 0 && t_i < 16) acc[t_o] += xv[t_i] * wgt[kt];
            }
          }
        }
      }
    }

    float* yp = y + (size_t)b * 16384 + (size_t)idx * 16;
#pragma unroll
    for (int t = 0; t < 16; t += 4) {
      float4 v;
      v.x = fmaxf(acc[t] + bias, 0.f);
      v.y = fmaxf(acc[t + 1] + bias, 0.f);
      v.z = fmaxf(acc[t + 2] + bias, 0.f);
      v.w = fmaxf(acc[t + 3] + bias, 0.f);
      *(float4*)(yp + t) = v;
    }
  }
}

__global__ __launch_bounds__(256) void conv_l5(const float* __restrict__ x,
                                               const float* __restrict__ w5,
                                               const float* __restrict__ b5,
                                               float* __restrict__ out) {
  const int b = blockIdx.x;
  const int tid = threadIdx.x;  // = w*16 + t
  const float* xb = x + (size_t)b * 16384 + tid;
  float s = b5[0];
#pragma unroll
  for (int k = 0; k < 64; ++k) s += xb[k * 256] * w5[k];
  out[(size_t)b * 256 + tid] = 1.f / (1.f + expf(-s));
}

extern "C" void kernel_launch(void* const* d_in, const int* in_sizes, int n_in,
                              void* d_out, int out_size, void* d_ws, size_t ws_size,
                              hipStream_t stream) {
  const float* corr = (const float*)d_in[0];
  const float* w1 = (const float*)d_in[1];
  const float* b1 = (const float*)d_in[2];
  const float* w2 = (const float*)d_in[3];
  const float* b2 = (const float*)d_in[4];
  const float* w3 = (const float*)d_in[5];
  const float* b3 = (const float*)d_in[6];
  const float* w4 = (const float*)d_in[7];
  const float* b4 = (const float*)d_in[8];
  const float* w5 = (const float*)d_in[9];
  const float* b5 = (const float*)d_in[10];

  float* y1 = (float*)d_ws;                       // 16 MB
  float* y2 = y1 + (size_t)256 * 16384;           // 16 MB

  conv_l1<<<512, 256, 0, stream>>>(corr, w1, b1, y1);
  conv_mid<7, 3><<<512, 256, 0, stream>>>(y1, w2, b2, y2);
  conv_mid<5, 2><<<512, 256, 0, stream>>>(y2, w3, b3, y1);
  conv_mid<3, 1><<<512, 256, 0, stream>>>(y1, w4, b4, y2);
  conv_l5<<<256, 256, 0, stream>>>(y2, w5, b5, (float*)d_out);
}

// Round 3
// 872.966 us; speedup vs baseline: 5.0855x; 4.2149x over previous
//
#include <hip/hip_runtime.h>
#include <math.h>

// Layer shapes:
//  x0 = corr: (256, dh=256, wt=256) viewed as (b, d,h, w,t) with dh=d*16+h, wt=w*16+t
//  L1: w1 (17,17,9,9) pad 4 -> y1 (256, dh_o=64, wt=256), relu   [88% of FLOPs -> MFMA]
//  L2: w2 (7,7,7,7)  pad 3 -> y2 same, relu                      [vector, unchanged]
//  L3: w3 (5,5,5,5)  pad 2 -> relu
//  L4: w4 (3,3,3,3)  pad 1 -> relu
//  L5: w5 (8,8,1,1)  pad 0 -> sigmoid -> out (256,1,16,16)
//
// R3: L1 reformulated as 81 (kw,kt)-tap GEMMs on mfma_f32_16x16x32_bf16.
//   D[m=wt_o][n=dh_o] += A[m][k=dh_i] * B[k][n]
//   A[m][k]  = x[b][dh_i][w_o+kw-4, t_o+kt-4]  (zero row for OOB t; uniform skip for OOB w)
//   B[k][n]  = w1[d_i-d_o+4, h_i-h_o+4, kw, kt] (banded; shared across images ->
//              precomputed once in MFMA-fragment order in global scratch)
// K=256 split into 4 quarters of 64 so LDS (XT quarter 37 KB + B dbuf 16 KB) < 64 KB.

typedef short bf16x8 __attribute__((ext_vector_type(8)));
typedef float f32x4 __attribute__((ext_vector_type(4)));

__device__ __forceinline__ unsigned short f2bf(float f) {
  unsigned int u = __float_as_uint(f);
  u += 0x7fffu + ((u >> 16) & 1u);  // RNE
  return (unsigned short)(u >> 16);
}

// ---------------- B-matrix precompute: Bg[kwkt][chunk8][n_tile4][lane64][j8] bf16 ----
__global__ __launch_bounds__(256) void build_B(const float* __restrict__ w1,
                                               unsigned short* __restrict__ Bg) {
  const int gid = blockIdx.x * 256 + threadIdx.x;  // 81*8*4*64 = 165888 threads exactly
  const int lane = gid & 63;
  const int n_tile = (gid >> 6) & 3;
  const int chunk = (gid >> 8) & 7;
  const int kwkt = gid >> 11;  // 0..80
  const int kw = kwkt / 9, kt = kwkt % 9;
  const int dh_o = n_tile * 16 + (lane & 15);
  const int d_o = dh_o >> 3, h_o = dh_o & 7;
  const int kbase = chunk * 32 + (lane >> 4) * 8;
  unsigned int pk[4];
#pragma unroll
  for (int p = 0; p < 4; ++p) {
    unsigned short lo, hi;
#pragma unroll
    for (int s = 0; s < 2; ++s) {
      const int j = p * 2 + s;
      const int dh_i = kbase + j;
      const int d_i = dh_i >> 4, h_i = dh_i & 15;
      const int kd = d_i - d_o + 4, kh = h_i - h_o + 4;
      float v = 0.f;
      if (kd >= 0 && kd < 17 && kh >= 0 && kh < 17)
        v = w1[((kd * 17 + kh) * 9 + kw) * 9 + kt];
      if (s == 0) lo = f2bf(v); else hi = f2bf(v);
    }
    pk[p] = (unsigned int)lo | ((unsigned int)hi << 16);
  }
  *(int4*)(Bg + (size_t)gid * 8) = make_int4(pk[0], pk[1], pk[2], pk[3]);
}

// ---------------- L1 MFMA kernel: one image per block, 4 waves, 64x64 C-tile/wave ----
#define XTS 72  // XT row stride in shorts (64 dh + 8 pad; 144 B keeps b128 align, spreads banks)

__global__ __launch_bounds__(256) void conv_l1_mfma(const float* __restrict__ x,
                                                    const unsigned short* __restrict__ Bg,
                                                    const float* __restrict__ b1,
                                                    float* __restrict__ y) {
  __shared__ __align__(16) unsigned short XT[257 * XTS];  // 37,008 B (row 256 = zeros)
  __shared__ __align__(16) unsigned short Bs[2][4096];    // 2 x 8,192 B
  const int b = blockIdx.x;
  const int tid = threadIdx.x;
  const int lane = tid & 63;
  const int wave = tid >> 6;
  const int quad = lane >> 4;
  const int tl = lane & 15;
  const float* xb = x + (size_t)b * 65536;

  f32x4 acc[4][4] = {};  // [m_tile][n_tile]

  if (tid < 9) *(int4*)&XT[256 * XTS + tid * 8] = make_int4(0, 0, 0, 0);

  for (int kq = 0; kq < 4; ++kq) {
    __syncthreads();  // prior XT/Bs consumers done
    // stage XT quarter: XT[wt][dh_local] = bf16(x[b][kq*64+dh_local][wt]); 2 dh packed/b32
#pragma unroll
    for (int it = 0; it < 8; ++it) {
      const int i = tid + it * 256;        // (dhp, wtq): 32 x 64
      const int dhp = i >> 6, wtq = i & 63;
      const float4 r0 = *(const float4*)(xb + ((size_t)(kq * 64 + 2 * dhp) * 256) + wtq * 4);
      const float4 r1 = *(const float4*)(xb + ((size_t)(kq * 64 + 2 * dhp + 1) * 256) + wtq * 4);
      const float a0[4] = {r0.x, r0.y, r0.z, r0.w};
      const float a1[4] = {r1.x, r1.y, r1.z, r1.w};
#pragma unroll
      for (int j = 0; j < 4; ++j) {
        const unsigned int p = (unsigned int)f2bf(a0[j]) | ((unsigned int)f2bf(a1[j]) << 16);
        *(unsigned int*)&XT[(wtq * 4 + j) * XTS + dhp * 2] = p;
      }
    }
    // prefetch B frags for kwkt=0 of this quarter (32 B/thread, coalesced)
    const unsigned short* BgQ = Bg + (size_t)(kq * 2) * 2048;  // + kwkt*8*2048
    int4 pf0 = *(const int4*)(BgQ + tid * 16);
    int4 pf1 = *(const int4*)(BgQ + tid * 16 + 8);
    __syncthreads();  // XT visible

    int kw = 0, kt = 0;
    for (int kwkt = 0; kwkt < 81; ++kwkt) {
      const int buf = kwkt & 1;
      *(int4*)&Bs[buf][tid * 16] = pf0;
      *(int4*)&Bs[buf][tid * 16 + 8] = pf1;
      __syncthreads();  // Bs[buf] ready
      if (kwkt < 80) {
        const unsigned short* p = Bg + ((size_t)(kwkt + 1) * 8 + kq * 2) * 2048;
        pf0 = *(const int4*)(p + tid * 16);
        pf1 = *(const int4*)(p + tid * 16 + 8);
      }
      // A row addressing for this tap
      const int t_i = tl + kt - 4;
      const bool tv = (t_i >= 0) && (t_i < 16);
      int rowoff[4];
      bool mv[4];
#pragma unroll
      for (int m = 0; m < 4; ++m) {
        const int w_o = wave * 4 + m;          // wave-uniform
        const int w_i = w_o + kw - 4;
        mv[m] = (w_i >= 0) && (w_i < 16);
        const int row = tv ? (w_i * 16 + t_i) : 256;
        rowoff[m] = row * XTS + quad * 8;
      }
#pragma unroll
      for (int chunk = 0; chunk < 2; ++chunk) {
        bf16x8 bfr[4];
#pragma unroll
        for (int n = 0; n < 4; ++n)
          bfr[n] = *(const bf16x8*)&Bs[buf][(chunk * 4 + n) * 512 + lane * 8];
#pragma unroll
        for (int m = 0; m < 4; ++m) {
          if (mv[m]) {
            const bf16x8 afr = *(const bf16x8*)&XT[rowoff[m] + chunk * 32];
#pragma unroll
            for (int n = 0; n < 4; ++n)
              acc[m][n] = __builtin_amdgcn_mfma_f32_16x16x32_bf16(afr, bfr[n], acc[m][n], 0, 0, 0);
          }
        }
      }
      if (++kt == 9) { kt = 0; ++kw; }
    }
  }

  // epilogue: bias + relu, store fp32.  D layout: n(col)=lane&15, m(row)=quad*4+reg
  const float bias = b1[0];
  float* yb = y + (size_t)b * 16384;
#pragma unroll
  for (int m = 0; m < 4; ++m) {
#pragma unroll
    for (int n = 0; n < 4; ++n) {
      const int dh_o = n * 16 + tl;
      const int wt0 = wave * 64 + m * 16 + quad * 4;
      float4 v;
      v.x = fmaxf(acc[m][n][0] + bias, 0.f);
      v.y = fmaxf(acc[m][n][1] + bias, 0.f);
      v.z = fmaxf(acc[m][n][2] + bias, 0.f);
      v.w = fmaxf(acc[m][n][3] + bias, 0.f);
      *(float4*)&yb[(size_t)dh_o * 256 + wt0] = v;
    }
  }
}

// ---------------- mid layers (unchanged from R2) -------------------------------------
#define RS 20

template <int KSZ, int PAD>
__global__ __launch_bounds__(256) void conv_mid(const float* __restrict__ x,
                                                const float* __restrict__ w,
                                                const float* __restrict__ bptr,
                                                float* __restrict__ y) {
  __shared__ float Xs[8 * 8 * 16 * RS];
  const int blk = blockIdx.x;
  const int b = blk >> 1;
  const int jbase = (blk & 1) * 2;
  const int tid = threadIdx.x;
  const float* xb = x + (size_t)b * 16384;
  {
    const float4* src = (const float4*)xb;
    for (int i = tid; i < 4096; i += 256) {
      const int r = i >> 2, t4 = i & 3;
      *(float4*)&Xs[r * RS + t4 * 4] = src[i];
    }
  }
  __syncthreads();
  const float bias = bptr[0];

  for (int jj = 0; jj < 2; ++jj) {
    const int idx = tid + 256 * (jbase + jj);
    const int w_o = idx & 15;
    const int h_o = (idx >> 4) & 7;
    const int d_o = idx >> 7;
    float acc[16];
#pragma unroll
    for (int t = 0; t < 16; ++t) acc[t] = 0.f;

    for (int d_i = 0; d_i < 8; ++d_i) {
      const int kd = d_i - d_o + PAD;
      if (kd < 0 || kd >= KSZ) continue;
      for (int h_i = 0; h_i < 8; ++h_i) {
        const int kh = h_i - h_o + PAD;
        const bool vh = (kh >= 0) && (kh < KSZ);
        const int khc = vh ? kh : 0;
        const float* wrow = w + (kd * KSZ + khc) * (KSZ * KSZ);
        for (int kw = 0; kw < KSZ; ++kw) {
          const int w_i = w_o + kw - PAD;
          const bool vin = (w_i >= 0) && (w_i < 16);
          const bool vw = vh && vin;
          const int wic = vin ? w_i : 0;
          const float* xr = &Xs[((d_i * 8 + h_i) * 16 + wic) * RS];
          float xv[16];
#pragma unroll
          for (int t = 0; t < 16; t += 4) {
            float4 v = *(const float4*)(xr + t);
            xv[t] = v.x; xv[t + 1] = v.y; xv[t + 2] = v.z; xv[t + 3] = v.w;
          }
          float wgt[KSZ];
#pragma unroll
          for (int ktt = 0; ktt < KSZ; ++ktt)
            wgt[ktt] = vw ? wrow[kw * KSZ + ktt] : 0.f;
#pragma unroll
          for (int ktt = 0; ktt < KSZ; ++ktt) {
#pragma unroll
            for (int t_o = 0; t_o < 16; ++t_o) {
              const int t_i2 = t_o + ktt - PAD;
              if (t_i2 >= 0 && t_i2 < 16) acc[t_o] += xv[t_i2] * wgt[ktt];
            }
          }
        }
      }
    }

    float* yp = y + (size_t)b * 16384 + (size_t)idx * 16;
#pragma unroll
    for (int t = 0; t < 16; t += 4) {
      float4 v;
      v.x = fmaxf(acc[t] + bias, 0.f);
      v.y = fmaxf(acc[t + 1] + bias, 0.f);
      v.z = fmaxf(acc[t + 2] + bias, 0.f);
      v.w = fmaxf(acc[t + 3] + bias, 0.f);
      *(float4*)(yp + t) = v;
    }
  }
}

__global__ __launch_bounds__(256) void conv_l5(const float* __restrict__ x,
                                               const float* __restrict__ w5,
                                               const float* __restrict__ b5,
                                               float* __restrict__ out) {
  const int b = blockIdx.x;
  const int tid = threadIdx.x;
  const float* xb = x + (size_t)b * 16384 + tid;
  float s = b5[0];
#pragma unroll
  for (int k = 0; k < 64; ++k) s += xb[k * 256] * w5[k];
  out[(size_t)b * 256 + tid] = 1.f / (1.f + expf(-s));
}

extern "C" void kernel_launch(void* const* d_in, const int* in_sizes, int n_in,
                              void* d_out, int out_size, void* d_ws, size_t ws_size,
                              hipStream_t stream) {
  const float* corr = (const float*)d_in[0];
  const float* w1 = (const float*)d_in[1];
  const float* b1 = (const float*)d_in[2];
  const float* w2 = (const float*)d_in[3];
  const float* b2 = (const float*)d_in[4];
  const float* w3 = (const float*)d_in[5];
  const float* b3 = (const float*)d_in[6];
  const float* w4 = (const float*)d_in[7];
  const float* b4 = (const float*)d_in[8];
  const float* w5 = (const float*)d_in[9];
  const float* b5 = (const float*)d_in[10];

  float* y1 = (float*)d_ws;                                  // 16 MB
  float* y2 = y1 + (size_t)256 * 16384;                      // 16 MB
  unsigned short* Bg = (unsigned short*)y2;                  // 2.65 MB, dead after L1

  build_B<<<648, 256, 0, stream>>>(w1, Bg);
  conv_l1_mfma<<<256, 256, 0, stream>>>(corr, Bg, b1, y1);
  conv_mid<7, 3><<<512, 256, 0, stream>>>(y1, w2, b2, y2);
  conv_mid<5, 2><<<512, 256, 0, stream>>>(y2, w3, b3, y1);
  conv_mid<3, 1><<<512, 256, 0, stream>>>(y1, w4, b4, y2);
  conv_l5<<<256, 256, 0, stream>>>(y2, w5, b5, (float*)d_out);
}

// Round 4
// 317.784 us; speedup vs baseline: 13.9701x; 2.7470x over previous
//
#include <hip/hip_runtime.h>
#include <math.h>

// Net (per image b of 256):  x: (dh=256, wt=256), dh=d*16+h, wt=w*16+t
//  L1: w1 (17,17,9,9) pad4 -> (dh_o=64, wt=256) relu      [MFMA, 81 taps, K=256]
//  L2: w2 (7,7,7,7)  pad3 -> same, relu                   [MFMA, 49 taps, K=64]
//  L3: w3 (5,5,5,5)  pad2 -> relu                         [MFMA, 25 taps]
//  L4: w4 (3,3,3,3)  pad1 -> relu                         [MFMA,  9 taps]
//  L5: w5 (8,8)      -> sigmoid -> out (256,16,16)        [vector dot]
//
// R4: per-(kw,kt)-tap banded GEMM for ALL conv layers.
//   D[m=wt_o][n=dh_o] += A[m][k=dh_i] B[k][n],  A = XT (LDS, bf16, transposed,
//   shifted rows; OOB -> zero row 256), B = fragment-ordered global (L2-hit,
//   16B/lane coalesced) -> NO per-tap LDS staging, NO per-tap barriers.
//   Register-double-buffered A/B prefetch (2-deep pipeline).
// Mids run IN-PLACE on one activation buffer (block reads whole image to LDS
// before writing back). ws use: 16 MB act + 3.3 MB B matrices.

typedef short bf16x8 __attribute__((ext_vector_type(8)));
typedef float f32x4 __attribute__((ext_vector_type(4)));

#define XTS 72  // XT row stride in shorts (16B-aligned rows, banks spread)

__device__ __forceinline__ unsigned short f2bf(float f) {
  unsigned int u = __float_as_uint(f);
  u += 0x7fffu + ((u >> 16) & 1u);  // RNE
  return (unsigned short)(u >> 16);
}

// ---------------- B-matrix precompute (all layers in one kernel) -------------
// L1 frag layout: gid = ((kwkt*8 + chunk)*4 + n_tile)*64 + lane, 8 shorts each
//   k = chunk*32 + (lane>>4)*8 + j (dh_i, 16x16), n = n_tile*16 + (lane&15) (dh_o, 8x8)
// Mid layout:     gid = ((tap*2 + chunk)*4 + n_tile)*64 + lane; dh_i is 8x8.
template <int KSZ, int PAD>
__device__ __forceinline__ void build_mid(const float* __restrict__ w,
                                          unsigned short* __restrict__ Bg, int gid) {
  const int lane = gid & 63;
  const int n_tile = (gid >> 6) & 3;
  const int chunk = (gid >> 8) & 1;
  const int tap = gid >> 9;
  const int kw = tap / KSZ, kt = tap - kw * KSZ;
  const int dh_o = n_tile * 16 + (lane & 15);
  const int d_o = dh_o >> 3, h_o = dh_o & 7;
  const int kbase = chunk * 32 + (lane >> 4) * 8;
  unsigned int pk[4];
#pragma unroll
  for (int p = 0; p < 4; ++p) {
    unsigned short half[2];
#pragma unroll
    for (int s = 0; s < 2; ++s) {
      const int k = kbase + p * 2 + s;
      const int d_i = k >> 3, h_i = k & 7;
      const int kd = d_i - d_o + PAD, kh = h_i - h_o + PAD;
      float v = 0.f;
      if (kd >= 0 && kd < KSZ && kh >= 0 && kh < KSZ)
        v = w[((kd * KSZ + kh) * KSZ + kw) * KSZ + kt];
      half[s] = f2bf(v);
    }
    pk[p] = (unsigned int)half[0] | ((unsigned int)half[1] << 16);
  }
  *(int4*)(Bg + (size_t)gid * 8) = make_int4(pk[0], pk[1], pk[2], pk[3]);
}

__global__ __launch_bounds__(256) void build_all(const float* __restrict__ w1,
                                                 const float* __restrict__ w2,
                                                 const float* __restrict__ w3,
                                                 const float* __restrict__ w4,
                                                 unsigned short* __restrict__ Bg1,
                                                 unsigned short* __restrict__ Bg2,
                                                 unsigned short* __restrict__ Bg3,
                                                 unsigned short* __restrict__ Bg4) {
  const int bid = blockIdx.x, tid = threadIdx.x;
  if (bid < 648) {  // L1: 81 taps * 8 chunks * 4 ntiles * 64 lanes
    const int gid = bid * 256 + tid;
    const int lane = gid & 63;
    const int n_tile = (gid >> 6) & 3;
    const int chunk = (gid >> 8) & 7;
    const int kwkt = gid >> 11;
    const int kw = kwkt / 9, kt = kwkt - kw * 9;
    const int dh_o = n_tile * 16 + (lane & 15);
    const int d_o = dh_o >> 3, h_o = dh_o & 7;
    const int kbase = chunk * 32 + (lane >> 4) * 8;
    unsigned int pk[4];
#pragma unroll
    for (int p = 0; p < 4; ++p) {
      unsigned short half[2];
#pragma unroll
      for (int s = 0; s < 2; ++s) {
        const int k = kbase + p * 2 + s;
        const int d_i = k >> 4, h_i = k & 15;
        const int kd = d_i - d_o + 4, kh = h_i - h_o + 4;
        float v = 0.f;
        if (kd >= 0 && kd < 17 && kh >= 0 && kh < 17)
          v = w1[((kd * 17 + kh) * 9 + kw) * 9 + kt];
        half[s] = f2bf(v);
      }
      pk[p] = (unsigned int)half[0] | ((unsigned int)half[1] << 16);
    }
    *(int4*)(Bg1 + (size_t)gid * 8) = make_int4(pk[0], pk[1], pk[2], pk[3]);
  } else if (bid < 746) {
    build_mid<7, 3>(w2, Bg2, (bid - 648) * 256 + tid);
  } else if (bid < 796) {
    build_mid<5, 2>(w3, Bg3, (bid - 746) * 256 + tid);
  } else {
    build_mid<3, 1>(w4, Bg4, (bid - 796) * 256 + tid);
  }
}

// ---------------- shared tap-loop pieces -------------------------------------
__device__ __forceinline__ void mfma_block(const bf16x8 (&A)[8], const bf16x8 (&B)[8],
                                           f32x4 (&acc)[4][4]) {
#pragma unroll
  for (int c = 0; c < 2; ++c)
#pragma unroll
    for (int m = 0; m < 4; ++m)
#pragma unroll
      for (int n = 0; n < 4; ++n)
        acc[m][n] = __builtin_amdgcn_mfma_f32_16x16x32_bf16(A[c * 4 + m], B[c * 4 + n],
                                                            acc[m][n], 0, 0, 0);
}

template <int KSZ, int PAD, int CHTOT>
__device__ __forceinline__ void load_tap(const unsigned short* XT,
                                         const unsigned short* __restrict__ Bg,
                                         int chbase, int kwkt, int wave, int lane,
                                         int quad, int tl, bf16x8 (&A)[8], bf16x8 (&B)[8]) {
  const int kw = kwkt / KSZ, kt = kwkt - kw * KSZ;
  const int t_i = tl + kt - PAD;
  const bool tv = (unsigned)t_i < 16u;
  int ro[4];
#pragma unroll
  for (int m = 0; m < 4; ++m) {
    const int w_i = wave * 4 + m + kw - PAD;
    const bool v = tv && ((unsigned)w_i < 16u);
    const int row = v ? (w_i * 16 + t_i) : 256;  // row 256 = zeros
    ro[m] = row * XTS + quad * 8;
  }
#pragma unroll
  for (int c = 0; c < 2; ++c)
#pragma unroll
    for (int m = 0; m < 4; ++m)
      A[c * 4 + m] = *(const bf16x8*)&XT[ro[m] + c * 32];
#pragma unroll
  for (int c = 0; c < 2; ++c)
#pragma unroll
    for (int n = 0; n < 4; ++n)
      B[c * 4 + n] = *(const bf16x8*)(Bg + (((size_t)(kwkt * CHTOT + chbase + c) * 4 + n) << 9) +
                                      lane * 8);
}

#define TAP_PIPELINE(NT, LOADCALL)                    \
  {                                                   \
    bf16x8 A0[8], B0[8], A1[8], B1[8];                \
    LOADCALL(0, A0, B0);                              \
    int k2 = 0;                                       \
    while (true) {                                    \
      if (k2 + 1 < (NT)) LOADCALL(k2 + 1, A1, B1);    \
      mfma_block(A0, B0, acc);                        \
      if (++k2 >= (NT)) break;                        \
      if (k2 + 1 < (NT)) LOADCALL(k2 + 1, A0, B0);    \
      mfma_block(A1, B1, acc);                        \
      if (++k2 >= (NT)) break;                        \
    }                                                 \
  }

// ---------------- L1: K=256 in 4 LDS quarters --------------------------------
__global__ __launch_bounds__(256) void conv_l1_mfma(const float* __restrict__ x,
                                                    const unsigned short* __restrict__ Bg,
                                                    const float* __restrict__ b1,
                                                    float* __restrict__ y) {
  __shared__ __align__(16) unsigned short XT[257 * XTS];
  const int b = blockIdx.x;
  const int tid = threadIdx.x;
  const int lane = tid & 63, wave = tid >> 6;
  const int quad = lane >> 4, tl = lane & 15;
  const float* xb = x + (size_t)b * 65536;
  f32x4 acc[4][4] = {};

  if (tid < 9) *(int4*)&XT[256 * XTS + tid * 8] = make_int4(0, 0, 0, 0);

  for (int kq = 0; kq < 4; ++kq) {
    __syncthreads();
#pragma unroll
    for (int it = 0; it < 8; ++it) {
      const int i = tid + it * 256;
      const int dhp = i >> 6, wtq = i & 63;
      const float4 r0 = *(const float4*)(xb + (size_t)(kq * 64 + 2 * dhp) * 256 + wtq * 4);
      const float4 r1 = *(const float4*)(xb + (size_t)(kq * 64 + 2 * dhp + 1) * 256 + wtq * 4);
      const float a0[4] = {r0.x, r0.y, r0.z, r0.w};
      const float a1[4] = {r1.x, r1.y, r1.z, r1.w};
#pragma unroll
      for (int j = 0; j < 4; ++j) {
        const unsigned int p = (unsigned int)f2bf(a0[j]) | ((unsigned int)f2bf(a1[j]) << 16);
        *(unsigned int*)&XT[(wtq * 4 + j) * XTS + dhp * 2] = p;
      }
    }
    __syncthreads();
#define LT_L1(KK, AA, BB) load_tap<9, 4, 8>(XT, Bg, kq * 2, (KK), wave, lane, quad, tl, AA, BB)
    TAP_PIPELINE(81, LT_L1)
#undef LT_L1
  }

  const float bias = b1[0];
  float* yb = y + (size_t)b * 16384;
#pragma unroll
  for (int m = 0; m < 4; ++m)
#pragma unroll
    for (int n = 0; n < 4; ++n) {
      const int dh_o = n * 16 + tl;
      const int wt0 = wave * 64 + m * 16 + quad * 4;
      float4 v;
      v.x = fmaxf(acc[m][n][0] + bias, 0.f);
      v.y = fmaxf(acc[m][n][1] + bias, 0.f);
      v.z = fmaxf(acc[m][n][2] + bias, 0.f);
      v.w = fmaxf(acc[m][n][3] + bias, 0.f);
      *(float4*)&yb[(size_t)dh_o * 256 + wt0] = v;
    }
}

// ---------------- mid layers: K=64, in-place ---------------------------------
template <int KSZ, int PAD, int NT>
__global__ __launch_bounds__(256) void conv_mid_mfma(float* __restrict__ y,
                                                     const unsigned short* __restrict__ Bg,
                                                     const float* __restrict__ bptr) {
  __shared__ __align__(16) unsigned short XT[257 * XTS];
  const int b = blockIdx.x;
  const int tid = threadIdx.x;
  const int lane = tid & 63, wave = tid >> 6;
  const int quad = lane >> 4, tl = lane & 15;
  float* yb = y + (size_t)b * 16384;
  f32x4 acc[4][4] = {};

  if (tid < 9) *(int4*)&XT[256 * XTS + tid * 8] = make_int4(0, 0, 0, 0);
#pragma unroll
  for (int it = 0; it < 8; ++it) {
    const int i = tid + it * 256;
    const int dhp = i >> 6, wtq = i & 63;
    const float4 r0 = *(const float4*)(yb + (size_t)(2 * dhp) * 256 + wtq * 4);
    const float4 r1 = *(const float4*)(yb + (size_t)(2 * dhp + 1) * 256 + wtq * 4);
    const float a0[4] = {r0.x, r0.y, r0.z, r0.w};
    const float a1[4] = {r1.x, r1.y, r1.z, r1.w};
#pragma unroll
    for (int j = 0; j < 4; ++j) {
      const unsigned int p = (unsigned int)f2bf(a0[j]) | ((unsigned int)f2bf(a1[j]) << 16);
      *(unsigned int*)&XT[(wtq * 4 + j) * XTS + dhp * 2] = p;
    }
  }
  __syncthreads();
#define LT_MID(KK, AA, BB) load_tap<KSZ, PAD, 2>(XT, Bg, 0, (KK), wave, lane, quad, tl, AA, BB)
  TAP_PIPELINE(NT, LT_MID)
#undef LT_MID

  const float bias = bptr[0];
#pragma unroll
  for (int m = 0; m < 4; ++m)
#pragma unroll
    for (int n = 0; n < 4; ++n) {
      const int dh_o = n * 16 + tl;
      const int wt0 = wave * 64 + m * 16 + quad * 4;
      float4 v;
      v.x = fmaxf(acc[m][n][0] + bias, 0.f);
      v.y = fmaxf(acc[m][n][1] + bias, 0.f);
      v.z = fmaxf(acc[m][n][2] + bias, 0.f);
      v.w = fmaxf(acc[m][n][3] + bias, 0.f);
      *(float4*)&yb[(size_t)dh_o * 256 + wt0] = v;
    }
}

// ---------------- L5 ---------------------------------------------------------
__global__ __launch_bounds__(256) void conv_l5(const float* __restrict__ x,
                                               const float* __restrict__ w5,
                                               const float* __restrict__ b5,
                                               float* __restrict__ out) {
  const int b = blockIdx.x;
  const int tid = threadIdx.x;
  const float* xb = x + (size_t)b * 16384 + tid;
  float s = b5[0];
#pragma unroll
  for (int k = 0; k < 64; ++k) s += xb[k * 256] * w5[k];
  out[(size_t)b * 256 + tid] = 1.f / (1.f + expf(-s));
}

extern "C" void kernel_launch(void* const* d_in, const int* in_sizes, int n_in,
                              void* d_out, int out_size, void* d_ws, size_t ws_size,
                              hipStream_t stream) {
  const float* corr = (const float*)d_in[0];
  const float* w1 = (const float*)d_in[1];
  const float* b1 = (const float*)d_in[2];
  const float* w2 = (const float*)d_in[3];
  const float* b2 = (const float*)d_in[4];
  const float* w3 = (const float*)d_in[5];
  const float* b3 = (const float*)d_in[6];
  const float* w4 = (const float*)d_in[7];
  const float* b4 = (const float*)d_in[8];
  const float* w5 = (const float*)d_in[9];
  const float* b5 = (const float*)d_in[10];

  float* A = (float*)d_ws;  // 16 MB activations, mids in-place
  unsigned short* Bg1 = (unsigned short*)((char*)d_ws + (16 << 20));
  unsigned short* Bg2 = Bg1 + (size_t)81 * 8 * 4 * 64 * 8;  // 1,327,104 shorts
  unsigned short* Bg3 = Bg2 + (size_t)49 * 2 * 4 * 64 * 8;  //   200,704
  unsigned short* Bg4 = Bg3 + (size_t)25 * 2 * 4 * 64 * 8;  //   102,400

  build_all<<<814, 256, 0, stream>>>(w1, w2, w3, w4, Bg1, Bg2, Bg3, Bg4);
  conv_l1_mfma<<<256, 256, 0, stream>>>(corr, Bg1, b1, A);
  conv_mid_mfma<7, 3, 49><<<256, 256, 0, stream>>>(A, Bg2, b2);
  conv_mid_mfma<5, 2, 25><<<256, 256, 0, stream>>>(A, Bg3, b3);
  conv_mid_mfma<3, 1, 9><<<256, 256, 0, stream>>>(A, Bg4, b4);
  conv_l5<<<256, 256, 0, stream>>>(A, w5, b5, (float*)d_out);
}